// Round 2
// baseline (55.892 us; speedup 1.0000x reference)
//
#include <hip/hip_runtime.h>

// Problem constants (fixed by setup_inputs):
//   x: (64,1,8,8) f32; KH=KW=5 -> oh=ow=4 -> N = 64*16 = 1024 rows, 25 feats/row
//   idx0:(128,36,6) in [0,25), lut0:(128,36,64)
//   idx1:(128, 6,6) in [0,36), lut1:(128, 6,64)
//   idx2:(128, 1,6) in [0, 6), lut2:(128, 1,64)
//   out: (64,128,4,4) f32 = 131072 elems
#define T_TREES 128
#define M0 36
#define M1 6
#define NNODES (M0 + M1 + 1)   // 43
#define NTHREADS 128
#define NROWS 1024
#define SLUT_ELEMS (T_TREES * NNODES * 64)   // 352256 floats = 1.41 MB

// ---------------- pre-pass: slut[t][node][64] = sigmoid(lut) ----------------
// Computed once per launch (vs 8x redundantly per tree when done per-block),
// and moves the node-LUT broadcast reads off the LDS pipe onto L1/L2.
__global__ __launch_bounds__(256) void sig_kernel(
    const float* __restrict__ lut0, const float* __restrict__ lut1,
    const float* __restrict__ lut2, float* __restrict__ slut) {
    int i = blockIdx.x * 256 + threadIdx.x;
    if (i >= SLUT_ELEMS) return;
    int j = i & 63;
    int tn = i >> 6;           // t*43 + node
    int t = tn / NNODES;
    int node = tn - t * NNODES;
    float v;
    if (node < M0)            v = lut0[(t * M0 + node) * 64 + j];
    else if (node < M0 + M1)  v = lut1[(t * M1 + (node - M0)) * 64 + j];
    else                      v = lut2[t * 64 + j];
    slut[i] = 1.f / (1.f + __expf(-v));
}

// One soft-LUT node: h = sum_{p,q,r} P[p*16+q*4+r] * Wa[p] * Wb[q] * Wc[r]
// sl: 64 sigmoided LUT values in GLOBAL memory (wave-uniform address, L1-hot).
__device__ __forceinline__ float lut_node(const float* __restrict__ sl,
                                          float a, float b, float c,
                                          float d, float e, float f) {
    float wa[4] = {(1.f - a) * (1.f - b), (1.f - a) * b, a * (1.f - b), a * b};
    float wb[4] = {(1.f - c) * (1.f - d), (1.f - c) * d, c * (1.f - d), c * d};
    float wc[4] = {(1.f - e) * (1.f - f), (1.f - e) * f, e * (1.f - f), e * f};
    float acc = 0.f;
#pragma unroll
    for (int p = 0; p < 4; ++p) {
        float tp = 0.f;
#pragma unroll
        for (int q = 0; q < 4; ++q) {
            const float4 P = *reinterpret_cast<const float4*>(sl + p * 16 + q * 4);
            float tq = P.x * wc[0] + P.y * wc[1] + P.z * wc[2] + P.w * wc[3];
            tp += tq * wb[q];
        }
        acc += tp * wa[p];
    }
    return acc;
}

__global__ __launch_bounds__(NTHREADS, 2) void clut_kernel(
    const float* __restrict__ x,
    const int* __restrict__ idx0, const int* __restrict__ idx1,
    const int* __restrict__ idx2, const float* __restrict__ slut,
    float* __restrict__ out) {
    // LDS: only the per-thread runtime-indexed columns (rule: runtime-indexed
    // arrays must live in LDS, not registers). Layout [k][tid] -> bank=tid%32,
    // conflict-free. h1 aliases feat (feat dead after layer 0).
    // Total: 25*128*4 + 36*128*4 = 31232 B -> 4-5 blocks/CU co-resident.
    __shared__ float feat[25 * NTHREADS];               // 12800 B (aliased by h1)
    __shared__ float h0[M0 * NTHREADS];                 // 18432 B
    float* h1 = feat;                                   // 6*128*4 = 3072 B reuse

    const int tid = threadIdx.x;
    const int t = blockIdx.y;
    const float* __restrict__ slt = slut + t * (NNODES * 64);

    // ---- per-thread features ----
    const int n = blockIdx.x * NTHREADS + tid;   // row id in [0,1024)
    const int b = n >> 4;
    const int s = n & 15;
    const int yy = s >> 2;
    const int xx = s & 3;
    const float* xb = x + b * 64 + yy * 8 + xx;
#pragma unroll
    for (int i = 0; i < 5; ++i)
#pragma unroll
        for (int j = 0; j < 5; ++j)
            feat[(i * 5 + j) * NTHREADS + tid] = xb[i * 8 + j];

    __syncthreads();   // only needed because h1 aliases feat across layers

    // ---- layer 0: 36 nodes over 25 features ----
#pragma unroll 2
    for (int m = 0; m < M0; ++m) {
        const int* id = idx0 + (t * M0 + m) * 6;
        float a = feat[id[0] * NTHREADS + tid];
        float bb = feat[id[1] * NTHREADS + tid];
        float c = feat[id[2] * NTHREADS + tid];
        float d = feat[id[3] * NTHREADS + tid];
        float e = feat[id[4] * NTHREADS + tid];
        float f = feat[id[5] * NTHREADS + tid];
        h0[m * NTHREADS + tid] = lut_node(slt + m * 64, a, bb, c, d, e, f);
    }

    __syncthreads();   // h1 will overwrite feat; all feat reads must be done

    // ---- layer 1: 6 nodes over 36 ----
#pragma unroll 2
    for (int m = 0; m < M1; ++m) {
        const int* id = idx1 + (t * M1 + m) * 6;
        float a = h0[id[0] * NTHREADS + tid];
        float bb = h0[id[1] * NTHREADS + tid];
        float c = h0[id[2] * NTHREADS + tid];
        float d = h0[id[3] * NTHREADS + tid];
        float e = h0[id[4] * NTHREADS + tid];
        float f = h0[id[5] * NTHREADS + tid];
        h1[m * NTHREADS + tid] = lut_node(slt + (M0 + m) * 64, a, bb, c, d, e, f);
    }

    // ---- layer 2: 1 node over 6 ----
    {
        const int* id = idx2 + t * 6;
        float a = h1[id[0] * NTHREADS + tid];
        float bb = h1[id[1] * NTHREADS + tid];
        float c = h1[id[2] * NTHREADS + tid];
        float d = h1[id[3] * NTHREADS + tid];
        float e = h1[id[4] * NTHREADS + tid];
        float f = h1[id[5] * NTHREADS + tid];
        float o = lut_node(slt + (M0 + M1) * 64, a, bb, c, d, e, f);
        out[b * (T_TREES * 16) + t * 16 + s] = o;
    }
}

extern "C" void kernel_launch(void* const* d_in, const int* in_sizes, int n_in,
                              void* d_out, int out_size, void* d_ws, size_t ws_size,
                              hipStream_t stream) {
    const float* x    = (const float*)d_in[0];
    const int*   idx0 = (const int*)  d_in[1];
    const float* lut0 = (const float*)d_in[2];
    const int*   idx1 = (const int*)  d_in[3];
    const float* lut1 = (const float*)d_in[4];
    const int*   idx2 = (const int*)  d_in[5];
    const float* lut2 = (const float*)d_in[6];
    float* out = (float*)d_out;
    float* slut = (float*)d_ws;   // 1.41 MB scratch

    sig_kernel<<<(SLUT_ELEMS + 255) / 256, 256, 0, stream>>>(lut0, lut1, lut2, slut);

    dim3 grid(NROWS / NTHREADS, T_TREES);   // (8, 128)
    clut_kernel<<<grid, NTHREADS, 0, stream>>>(x, idx0, idx1, idx2, slut, out);
}

// Round 3
// 55.527 us; speedup vs baseline: 1.0066x; 1.0066x over previous
//
#include <hip/hip_runtime.h>

// Problem constants (fixed by setup_inputs):
//   x: (64,1,8,8) f32; KH=KW=5 -> oh=ow=4 -> N = 64*16 = 1024 rows, 25 feats/row
//   idx0:(128,36,6) in [0,25), lut0:(128,36,64)
//   idx1:(128, 6,6) in [0,36), lut1:(128, 6,64)
//   idx2:(128, 1,6) in [0, 6), lut2:(128, 1,64)
//   out: (64,128,4,4) f32 = 131072 elems
#define T_TREES 128
#define M0 36
#define M1 6
#define NNODES (M0 + M1 + 1)   // 43
#define NROWS 1024
#define ROWS_PER_BLK 128
#define NTHREADS 256           // 2 node-groups x 128 rows
#define SLUT_ELEMS (T_TREES * NNODES * 64)   // 352256 floats = 1.41 MB

// ---------------- pre-pass: slut[t][node][64] = sigmoid(lut) ----------------
// float4-vectorized: 88064 float4s.
__global__ __launch_bounds__(256) void sig_kernel(
    const float* __restrict__ lut0, const float* __restrict__ lut1,
    const float* __restrict__ lut2, float* __restrict__ slut) {
    int i4 = blockIdx.x * 256 + threadIdx.x;
    if (i4 >= SLUT_ELEMS / 4) return;
    int j4 = i4 & 15;          // float4 index within node (16 per node)
    int tn = i4 >> 4;          // t*43 + node
    int t = tn / NNODES;
    int node = tn - t * NNODES;
    const float4* src;
    if (node < M0)            src = (const float4*)lut0 + (t * M0 + node) * 16 + j4;
    else if (node < M0 + M1)  src = (const float4*)lut1 + (t * M1 + (node - M0)) * 16 + j4;
    else                      src = (const float4*)lut2 + t * 16 + j4;
    float4 v = *src;
    float4 r;
    r.x = 1.f / (1.f + __expf(-v.x));
    r.y = 1.f / (1.f + __expf(-v.y));
    r.z = 1.f / (1.f + __expf(-v.z));
    r.w = 1.f / (1.f + __expf(-v.w));
    reinterpret_cast<float4*>(slut)[i4] = r;
}

// One soft-LUT node: h = sum_{p,q,r} P[p*16+q*4+r] * Wa[p] * Wb[q] * Wc[r]
// sl: 64 sigmoided LUT values (wave-uniform address, L1/L2-hot).
__device__ __forceinline__ float lut_node(const float* __restrict__ sl,
                                          float a, float b, float c,
                                          float d, float e, float f) {
    float wa[4] = {(1.f - a) * (1.f - b), (1.f - a) * b, a * (1.f - b), a * b};
    float wb[4] = {(1.f - c) * (1.f - d), (1.f - c) * d, c * (1.f - d), c * d};
    float wc[4] = {(1.f - e) * (1.f - f), (1.f - e) * f, e * (1.f - f), e * f};
    float acc = 0.f;
#pragma unroll
    for (int p = 0; p < 4; ++p) {
        float tp = 0.f;
#pragma unroll
        for (int q = 0; q < 4; ++q) {
            const float4 P = *reinterpret_cast<const float4*>(sl + p * 16 + q * 4);
            float tq = P.x * wc[0] + P.y * wc[1] + P.z * wc[2] + P.w * wc[3];
            tp += tq * wb[q];
        }
        acc += tp * wa[p];
    }
    return acc;
}

__global__ __launch_bounds__(NTHREADS) void clut_kernel(
    const float* __restrict__ x,
    const int* __restrict__ idx0, const int* __restrict__ idx1,
    const int* __restrict__ idx2, const float* __restrict__ slut,
    float* __restrict__ out) {
    // Per-thread runtime-indexed columns live in LDS, layout [k][row] ->
    // bank = row%32, conflict-free (2 lanes/bank = free).
    __shared__ float feat[25 * ROWS_PER_BLK];   // 12800 B
    __shared__ float h0[M0 * ROWS_PER_BLK];     // 18432 B
    __shared__ float h1[M1 * ROWS_PER_BLK];     //  3072 B   (34304 total)

    const int tid = threadIdx.x;
    const int g = tid >> 7;        // node-group, wave-uniform (waves 0,1 vs 2,3)
    const int r = tid & 127;       // row within chunk
    const int t = blockIdx.x;      // tree (fast dim -> same-tree blocks share XCD)
    const int chunk = blockIdx.y;
    const float* __restrict__ slt = slut + t * (NNODES * 64);

    // ---- features: both groups stage interleaved halves ----
    const int n = chunk * ROWS_PER_BLK + r;   // row id in [0,1024)
    const int b = n >> 4;
    const int s = n & 15;
    const float* xb = x + b * 64 + (s >> 2) * 8 + (s & 3);
    for (int k = g; k < 25; k += 2) {
        int i = k / 5;
        int j = k - 5 * i;
        feat[k * ROWS_PER_BLK + r] = xb[i * 8 + j];
    }
    __syncthreads();

    // ---- layer 0: 36 nodes, 18 per group ----
#pragma unroll 2
    for (int m = g * 18; m < g * 18 + 18; ++m) {
        const int* id = idx0 + (t * M0 + m) * 6;
        float a  = feat[id[0] * ROWS_PER_BLK + r];
        float bb = feat[id[1] * ROWS_PER_BLK + r];
        float c  = feat[id[2] * ROWS_PER_BLK + r];
        float d  = feat[id[3] * ROWS_PER_BLK + r];
        float e  = feat[id[4] * ROWS_PER_BLK + r];
        float f  = feat[id[5] * ROWS_PER_BLK + r];
        h0[m * ROWS_PER_BLK + r] = lut_node(slt + m * 64, a, bb, c, d, e, f);
    }
    __syncthreads();

    // ---- layer 1: 6 nodes, 3 per group ----
#pragma unroll
    for (int m = g * 3; m < g * 3 + 3; ++m) {
        const int* id = idx1 + (t * M1 + m) * 6;
        float a  = h0[id[0] * ROWS_PER_BLK + r];
        float bb = h0[id[1] * ROWS_PER_BLK + r];
        float c  = h0[id[2] * ROWS_PER_BLK + r];
        float d  = h0[id[3] * ROWS_PER_BLK + r];
        float e  = h0[id[4] * ROWS_PER_BLK + r];
        float f  = h0[id[5] * ROWS_PER_BLK + r];
        h1[m * ROWS_PER_BLK + r] = lut_node(slt + (M0 + m) * 64, a, bb, c, d, e, f);
    }
    __syncthreads();

    // ---- layer 2: 1 node (group 0 only, ~2% idle tail) ----
    if (g == 0) {
        const int* id = idx2 + t * 6;
        float a  = h1[id[0] * ROWS_PER_BLK + r];
        float bb = h1[id[1] * ROWS_PER_BLK + r];
        float c  = h1[id[2] * ROWS_PER_BLK + r];
        float d  = h1[id[3] * ROWS_PER_BLK + r];
        float e  = h1[id[4] * ROWS_PER_BLK + r];
        float f  = h1[id[5] * ROWS_PER_BLK + r];
        float o = lut_node(slt + (M0 + M1) * 64, a, bb, c, d, e, f);
        out[b * (T_TREES * 16) + t * 16 + s] = o;
    }
}

extern "C" void kernel_launch(void* const* d_in, const int* in_sizes, int n_in,
                              void* d_out, int out_size, void* d_ws, size_t ws_size,
                              hipStream_t stream) {
    const float* x    = (const float*)d_in[0];
    const int*   idx0 = (const int*)  d_in[1];
    const float* lut0 = (const float*)d_in[2];
    const int*   idx1 = (const int*)  d_in[3];
    const float* lut1 = (const float*)d_in[4];
    const int*   idx2 = (const int*)  d_in[5];
    const float* lut2 = (const float*)d_in[6];
    float* out = (float*)d_out;
    float* slut = (float*)d_ws;   // 1.41 MB scratch

    sig_kernel<<<(SLUT_ELEMS / 4 + 255) / 256, 256, 0, stream>>>(lut0, lut1, lut2, slut);

    dim3 grid(T_TREES, NROWS / ROWS_PER_BLK);   // (128, 8) tree-fastest
    clut_kernel<<<grid, NTHREADS, 0, stream>>>(x, idx0, idx1, idx2, slut, out);
}

// Round 4
// 25.807 us; speedup vs baseline: 2.1658x; 2.1517x over previous
//
#include <hip/hip_runtime.h>

// Problem constants (fixed by setup_inputs):
//   x: (64,1,8,8) f32 = 4096 floats = 16 KB TOTAL; KH=KW=5 -> oh=ow=4
//   rows n = b*16 + (oy*4+ox), N = 1024; feat[n,k] = x[b*64+(oy+i)*8+(ox+j)], k=i*5+j
//   idx0:(128,36,6) in [0,25), lut0:(128,36,64)
//   idx1:(128, 6,6) in [0,36), lut1:(128, 6,64)
//   idx2:(128, 1,6) in [0, 6), lut2:(128, 1,64)
//   out[b,t,oy,ox] = b*2048 + t*16 + s
#define T_TREES 128
#define M0 36
#define M1 6
#define NROWS 1024

__device__ __forceinline__ float sigmoidf(float v) {
    return 1.f / (1.f + __expf(-v));
}

// Trilinear-factorized LUT contraction; all indexing compile-time (stays in regs).
__device__ __forceinline__ float lut_node(const float* __restrict__ P,
                                          float a, float b, float c,
                                          float d, float e, float f) {
    float wa[4] = {(1.f - a) * (1.f - b), (1.f - a) * b, a * (1.f - b), a * b};
    float wb[4] = {(1.f - c) * (1.f - d), (1.f - c) * d, c * (1.f - d), c * d};
    float wc[4] = {(1.f - e) * (1.f - f), (1.f - e) * f, e * (1.f - f), e * f};
    float acc = 0.f;
#pragma unroll
    for (int p = 0; p < 4; ++p) {
        float tp = 0.f;
#pragma unroll
        for (int q = 0; q < 4; ++q) {
            const float* Pq = P + p * 16 + q * 4;
            float tq = Pq[0] * wc[0] + Pq[1] * wc[1] + Pq[2] * wc[2] + Pq[3] * wc[3];
            tp += tq * wb[q];
        }
        acc += tp * wa[p];
    }
    return acc;
}

// ============ layer 0, node-stationary: block = (tree t, node m) ============
// P hoisted to 64 registers outside the row loop -> inner loop is 6 LDS
// gathers + ~110 VALU, zero per-node reloads, no scalar/LDS lgkm mixing.
__global__ __launch_bounds__(256) void l0_kernel(
    const float* __restrict__ x, const int* __restrict__ idx0,
    const float* __restrict__ lut0, float* __restrict__ h0) {
    __shared__ float xs[4096];   // the ENTIRE x input (16 KB)
    __shared__ float Ps[64];

    const int tid = threadIdx.x;
    const int bx = blockIdx.x;           // bx = m*128 + t  (t fast -> per-tree XCD locality)
    const int t = bx & 127;
    const int m = bx >> 7;

    // stage all of x (4 float4 per thread, coalesced)
#pragma unroll
    for (int i = 0; i < 4; ++i)
        reinterpret_cast<float4*>(xs)[tid + i * 256] =
            reinterpret_cast<const float4*>(x)[tid + i * 256];

    // sigmoid this node's 64 LUT entries
    if (tid < 64) Ps[tid] = sigmoidf(lut0[(t * M0 + m) * 64 + tid]);
    __syncthreads();

    // hoist P into registers (row-invariant)
    float P[64];
#pragma unroll
    for (int i = 0; i < 16; ++i) {
        float4 v = reinterpret_cast<const float4*>(Ps)[i];
        P[4 * i] = v.x; P[4 * i + 1] = v.y; P[4 * i + 2] = v.z; P[4 * i + 3] = v.w;
    }

    // uniform idx -> window offsets di = i*8 + j  (k = i*5+j, k<25 -> i = (k*13)>>6)
    const int* id = idx0 + (t * M0 + m) * 6;
    int di[6];
#pragma unroll
    for (int k_ = 0; k_ < 6; ++k_) {
        int k = id[k_];
        int ii = (k * 13) >> 6;          // k/5 for k in [0,25)
        di[k_] = k + 3 * ii;             // i*8 + j
    }

    float* __restrict__ hout = h0 + (t * M0 + m) * NROWS;
#pragma unroll
    for (int u = 0; u < 4; ++u) {
        int row = u * 256 + tid;
        int b = row >> 4, s = row & 15;
        int xbase = b * 64 + (s >> 2) * 8 + (s & 3);
        float g0 = xs[xbase + di[0]];
        float g1 = xs[xbase + di[1]];
        float g2 = xs[xbase + di[2]];
        float g3 = xs[xbase + di[3]];
        float g4 = xs[xbase + di[4]];
        float g5 = xs[xbase + di[5]];
        hout[row] = lut_node(P, g0, g1, g2, g3, g4, g5);   // coalesced store
    }
}

// ============ layers 1+2 fused: block = (tree t, 256-row chunk) ============
__global__ __launch_bounds__(256) void l12_kernel(
    const float* __restrict__ h0, const int* __restrict__ idx1,
    const float* __restrict__ lut1, const int* __restrict__ idx2,
    const float* __restrict__ lut2, float* __restrict__ out) {
    __shared__ __align__(16) float Ps[(M1 + 1) * 64];   // 448 floats
    __shared__ float h1s[M1 * 256];                     // 6 KB

    const int tid = threadIdx.x;
    const int bx = blockIdx.x;           // bx = chunk*128 + t
    const int t = bx & 127;
    const int chunk = bx >> 7;

    for (int i = tid; i < (M1 + 1) * 64; i += 256) {
        float v = (i < M1 * 64) ? lut1[t * (M1 * 64) + i] : lut2[t * 64 + (i - M1 * 64)];
        Ps[i] = sigmoidf(v);
    }
    __syncthreads();

    const int row = chunk * 256 + tid;

    // layer 1: 6 nodes; h0 reads are coalesced (uniform column id, lane = row)
#pragma unroll
    for (int m = 0; m < M1; ++m) {
        const int* id = idx1 + (t * M1 + m) * 6;
        float g0 = h0[(t * M0 + id[0]) * NROWS + row];
        float g1 = h0[(t * M0 + id[1]) * NROWS + row];
        float g2 = h0[(t * M0 + id[2]) * NROWS + row];
        float g3 = h0[(t * M0 + id[3]) * NROWS + row];
        float g4 = h0[(t * M0 + id[4]) * NROWS + row];
        float g5 = h0[(t * M0 + id[5]) * NROWS + row];
        h1s[m * 256 + tid] = lut_node(Ps + m * 64, g0, g1, g2, g3, g4, g5);
    }
    __syncthreads();

    // layer 2: 1 node
    {
        const int* id = idx2 + t * 6;
        float g0 = h1s[id[0] * 256 + tid];
        float g1 = h1s[id[1] * 256 + tid];
        float g2 = h1s[id[2] * 256 + tid];
        float g3 = h1s[id[3] * 256 + tid];
        float g4 = h1s[id[4] * 256 + tid];
        float g5 = h1s[id[5] * 256 + tid];
        float o = lut_node(Ps + M1 * 64, g0, g1, g2, g3, g4, g5);
        int b = row >> 4, s = row & 15;
        out[b * (T_TREES * 16) + t * 16 + s] = o;
    }
}

// ============ fallback (ws too small): R1 self-contained kernel ============
__global__ __launch_bounds__(128) void clut_fb_kernel(
    const float* __restrict__ x,
    const int* __restrict__ idx0, const float* __restrict__ lut0,
    const int* __restrict__ idx1, const float* __restrict__ lut1,
    const int* __restrict__ idx2, const float* __restrict__ lut2,
    float* __restrict__ out) {
    __shared__ __align__(16) float slut[43 * 64];
    __shared__ float feat[25 * 128];
    __shared__ float h0[M0 * 128];
    __shared__ float h1[M1 * 128];

    const int tid = threadIdx.x;
    const int t = blockIdx.y;
    for (int i = tid; i < 43 * 64; i += 128) {
        float v;
        if (i < M0 * 64)              v = lut0[t * (M0 * 64) + i];
        else if (i < (M0 + M1) * 64)  v = lut1[t * (M1 * 64) + (i - M0 * 64)];
        else                          v = lut2[t * 64 + (i - (M0 + M1) * 64)];
        slut[i] = sigmoidf(v);
    }
    const int n = blockIdx.x * 128 + tid;
    const int b = n >> 4, s = n & 15;
    const float* xb = x + b * 64 + (s >> 2) * 8 + (s & 3);
#pragma unroll
    for (int i = 0; i < 5; ++i)
#pragma unroll
        for (int j = 0; j < 5; ++j)
            feat[(i * 5 + j) * 128 + tid] = xb[i * 8 + j];
    __syncthreads();
    for (int m = 0; m < M0; ++m) {
        const int* id = idx0 + (t * M0 + m) * 6;
        h0[m * 128 + tid] = lut_node(slut + m * 64,
            feat[id[0] * 128 + tid], feat[id[1] * 128 + tid], feat[id[2] * 128 + tid],
            feat[id[3] * 128 + tid], feat[id[4] * 128 + tid], feat[id[5] * 128 + tid]);
    }
    for (int m = 0; m < M1; ++m) {
        const int* id = idx1 + (t * M1 + m) * 6;
        h1[m * 128 + tid] = lut_node(slut + (M0 + m) * 64,
            h0[id[0] * 128 + tid], h0[id[1] * 128 + tid], h0[id[2] * 128 + tid],
            h0[id[3] * 128 + tid], h0[id[4] * 128 + tid], h0[id[5] * 128 + tid]);
    }
    {
        const int* id = idx2 + t * 6;
        float o = lut_node(slut + (M0 + M1) * 64,
            h1[id[0] * 128 + tid], h1[id[1] * 128 + tid], h1[id[2] * 128 + tid],
            h1[id[3] * 128 + tid], h1[id[4] * 128 + tid], h1[id[5] * 128 + tid]);
        out[b * (T_TREES * 16) + t * 16 + s] = o;
    }
}

extern "C" void kernel_launch(void* const* d_in, const int* in_sizes, int n_in,
                              void* d_out, int out_size, void* d_ws, size_t ws_size,
                              hipStream_t stream) {
    const float* x    = (const float*)d_in[0];
    const int*   idx0 = (const int*)  d_in[1];
    const float* lut0 = (const float*)d_in[2];
    const int*   idx1 = (const int*)  d_in[3];
    const float* lut1 = (const float*)d_in[4];
    const int*   idx2 = (const int*)  d_in[5];
    const float* lut2 = (const float*)d_in[6];
    float* out = (float*)d_out;

    const size_t h0_bytes = (size_t)T_TREES * M0 * NROWS * sizeof(float);  // 18.9 MB
    if (ws_size >= h0_bytes) {
        float* h0 = (float*)d_ws;
        l0_kernel<<<dim3(M0 * T_TREES), 256, 0, stream>>>(x, idx0, lut0, h0);
        l12_kernel<<<dim3(4 * T_TREES), 256, 0, stream>>>(h0, idx1, lut1, idx2, lut2, out);
    } else {
        dim3 grid(NROWS / 128, T_TREES);
        clut_fb_kernel<<<grid, 128, 0, stream>>>(x, idx0, lut0, idx1, lut1, idx2, lut2, out);
    }
}